// Round 1
// baseline (641.462 us; speedup 1.0000x reference)
//
#include <hip/hip_runtime.h>
#include <stdint.h>

// CTC loss forward, MI355X.
// Phase 1 (k_gather_exp): compact + exponentiate emissions.
//   El[b][t][d] = exp(log_probs[b,t,targets[b,d]]), d in [0,256)
//   Eb[b][t]    = exp(log_probs[b,t,0])  (blank)
// Phase 2 (k_ctc_alpha): one wave per sample. Lane owns 4 (label,blank)
//   state pairs; linear-domain alpha with per-lane power-of-2 offsets,
//   renormalized every 4 steps (exponent extraction, no transcendentals).
//   Emissions staged to LDS in 32-step double-buffered chunks via
//   global_load_lds (async DMA, wave-uniform dest base + lane*16).
// Phase 3 (k_reduce): mean over batch of nll/target_length.

#define CS 32
#define LN2F 0.69314718055994530942f

#define ASYNC_CP16(g, l)                                                     \
  __builtin_amdgcn_global_load_lds(                                          \
      (__attribute__((address_space(1))) void*)(g),                          \
      (__attribute__((address_space(3))) void*)(l), 16, 0, 0)
#define ASYNC_CP4(g, l)                                                      \
  __builtin_amdgcn_global_load_lds(                                          \
      (__attribute__((address_space(1))) void*)(g),                          \
      (__attribute__((address_space(3))) void*)(l), 4, 0, 0)

__global__ __launch_bounds__(256) void k_gather_exp(
    const float* __restrict__ lp, const int* __restrict__ tgt,
    const int* __restrict__ ilen, float* __restrict__ El,
    float* __restrict__ Eb, int T, int V, int S) {
  const int t = blockIdx.x;
  const int b = blockIdx.y;
  if (t >= ilen[b]) return;  // phase 2 never reads t >= T_b
  __shared__ float row[1024];  // V == 1024
  const float* src = lp + ((size_t)b * T + t) * V;
  const int tid = threadIdx.x;
  for (int i = tid; i < (V >> 2); i += blockDim.x)
    ((float4*)row)[i] = ((const float4*)src)[i];
  __syncthreads();
  for (int d = tid; d < S; d += blockDim.x) {
    const int lab = tgt[b * S + d];
    El[((size_t)b * T + t) * S + d] = __expf(row[lab]);
  }
  if (tid == 0) Eb[(size_t)b * T + t] = __expf(row[0]);
}

__global__ __launch_bounds__(64) void k_ctc_alpha(
    const float* __restrict__ El, const float* __restrict__ Eb,
    const int* __restrict__ tgt, const int* __restrict__ ilen,
    const int* __restrict__ tlen, float* __restrict__ nll_out, int T, int S) {
  const int b = blockIdx.x;
  const int lane = threadIdx.x;
  __shared__ __align__(16) float elbuf[2][CS][256];
  __shared__ float ebbuf[2][CS];

  const int Tb = ilen[b];
  const int U = tlen[b];

  // skip flags per pair p = 4*lane + j : skip iff p==0 (masked anyway) or
  // targets[p] != targets[p-1]
  const int4 tg = *(const int4*)(tgt + (size_t)b * S + 4 * lane);
  const int tprev = __shfl_up(tg.w, 1);
  const float sk0 = (lane == 0) ? 1.0f : ((tg.x != tprev) ? 1.0f : 0.0f);
  const float sk1 = (tg.y != tg.x) ? 1.0f : 0.0f;
  const float sk2 = (tg.z != tg.y) ? 1.0f : 0.0f;
  const float sk3 = (tg.w != tg.z) ? 1.0f : 0.0f;

  // alpha state: lane owns pairs p=4*lane..4*lane+3; pair p = states
  // (2p+1 label, 2p+2 blank). a0 = state 0 (lane 0 only; others stay 0).
  float aL0 = 0, aL1 = 0, aL2 = 0, aL3 = 0;
  float aB0 = 0, aB1 = 0, aB2 = 0, aB3 = 0;
  float a0 = 0;
  int o = 0;       // per-lane log2 offset: true alpha = a * 2^o
  float s = 1.0f;  // 2^(o_left - o): scale for incoming neighbor values

  const float* Elb = El + (size_t)b * T * 256;
  const float* Ebb = Eb + (size_t)b * T;

  // issue chunk 0
  {
    const int nrows = min(CS, T);
    for (int r = 0; r < nrows; ++r)
      ASYNC_CP16(Elb + (size_t)r * 256 + 4 * lane, &elbuf[0][r][0]);
    if (lane < nrows) ASYNC_CP4(Ebb + lane, &ebbuf[0][0]);
  }

  const int nchunks = (Tb + CS - 1) / CS;
  for (int c = 0; c < nchunks; ++c) {
    asm volatile("s_waitcnt vmcnt(0)" ::: "memory");
    __syncthreads();
    const int buf = c & 1;
    if ((c + 1) * CS < Tb) {  // prefetch next chunk into other buffer
      const int base = (c + 1) * CS;
      const int nrows = min(CS, T - base);
      const float* gEl = Elb + (size_t)base * 256 + 4 * lane;
      for (int r = 0; r < nrows; ++r)
        ASYNC_CP16(gEl + (size_t)r * 256, &elbuf[buf ^ 1][r][0]);
      if (lane < nrows) ASYNC_CP4(Ebb + base + lane, &ebbuf[buf ^ 1][0]);
    }
    const int nsteps = min(CS, Tb - c * CS);

    float4 elc = *(const float4*)&elbuf[buf][0][4 * lane];
    float ebc = ebbuf[buf][0];

    auto step = [&](int r) {
      float4 eln = elc;
      float ebn = ebc;
      if (r + 1 < nsteps) {  // LDS->reg prefetch one step ahead
        eln = *(const float4*)&elbuf[buf][r + 1][4 * lane];
        ebn = ebbuf[buf][r + 1];
      }
      const int t = c * CS + r;
      if (t == 0) {
        // alpha0: only states 0 and 1 live
        a0 = (lane == 0) ? ebc : 0.0f;
        aL0 = (lane == 0) ? elc.x : 0.0f;
      } else {
        float pL = __shfl_up(aL3, 1);  // state 2p-1 for p = 4*lane
        float pB = __shfl_up(aB3, 1);  // state 2p
        pL *= s;
        pB *= s;
        if (lane == 0) {
          pL = 0.0f;  // state -1 doesn't exist
          pB = a0;    // state 0
        }
        const float nB0 = (aB0 + aL0) * ebc;
        const float nB1 = (aB1 + aL1) * ebc;
        const float nB2 = (aB2 + aL2) * ebc;
        const float nB3 = (aB3 + aL3) * ebc;
        const float nL0 = (aL0 + pB + sk0 * pL) * elc.x;
        const float nL1 = (aL1 + aB0 + sk1 * aL0) * elc.y;
        const float nL2 = (aL2 + aB1 + sk2 * aL1) * elc.z;
        const float nL3 = (aL3 + aB2 + sk3 * aL2) * elc.w;
        a0 *= ebc;
        aL0 = nL0; aL1 = nL1; aL2 = nL2; aL3 = nL3;
        aB0 = nB0; aB1 = nB1; aB2 = nB2; aB3 = nB3;
      }
      if ((t & 3) == 3) {  // renorm: per-lane power-of-2 rescale
        float m = fmaxf(fmaxf(fmaxf(aL0, aL1), fmaxf(aL2, aL3)),
                        fmaxf(fmaxf(aB0, aB1), fmaxf(aB2, aB3)));
        m = fmaxf(m, a0);
        const bool nz = (m > 0.0f);
        const int mk = nz ? (((__float_as_int(m) >> 23) & 0xff) - 126) : 0;
        const int ocand = o + mk;
        const int oleft = __shfl_up(ocand, 1);
        // all-zero lanes adopt left neighbor's new offset (frontier moves
        // <= 8 states per 4 steps => at most into the adjacent lane)
        o = (nz || lane == 0) ? ocand : oleft;
        if (nz) {
          const float sc = __int_as_float((127 - mk) << 23);  // 2^-mk
          aL0 *= sc; aL1 *= sc; aL2 *= sc; aL3 *= sc;
          aB0 *= sc; aB1 *= sc; aB2 *= sc; aB3 *= sc;
          a0 *= sc;
        }
        int d = __shfl_up(o, 1) - o;
        d = max(-126, min(126, d));
        s = __int_as_float((d + 127) << 23);  // 2^d
      }
      elc = eln;
      ebc = ebn;
    };

    if (nsteps == CS) {
#pragma unroll 4
      for (int r = 0; r < CS; ++r) step(r);
    } else {
      for (int r = 0; r < nsteps; ++r) step(r);
    }
  }

  // read alpha_{Tb-1} at states 2U (pair U-1 blank) and 2U-1 (pair U-1 label)
  if (lane == ((U - 1) >> 2)) {
    const int j = (U - 1) & 3;
    float sv;
    if (j == 0)      sv = aL0 + aB0;
    else if (j == 1) sv = aL1 + aB1;
    else if (j == 2) sv = aL2 + aB2;
    else             sv = aL3 + aB3;
    float nll = -LN2F * (__log2f(sv) + (float)o);
    if (!(nll < 5e29f)) nll = 0.0f;  // zero_infinity (also catches NaN/inf)
    nll_out[b] = nll / (float)U;
  }
}

__global__ __launch_bounds__(64) void k_reduce(const float* __restrict__ nll,
                                               float* __restrict__ out,
                                               int B) {
  float v = 0.0f;
  for (int i = threadIdx.x; i < B; i += 64) v += nll[i];
  for (int off = 32; off > 0; off >>= 1) v += __shfl_down(v, off);
  if (threadIdx.x == 0) out[0] = v / (float)B;
}

extern "C" void kernel_launch(void* const* d_in, const int* in_sizes, int n_in,
                              void* d_out, int out_size, void* d_ws,
                              size_t ws_size, hipStream_t stream) {
  const float* lp = (const float*)d_in[0];
  const int* tgt = (const int*)d_in[1];
  const int* ilen = (const int*)d_in[2];
  const int* tlen = (const int*)d_in[3];

  const int B = in_sizes[2];
  const int S = in_sizes[1] / B;                              // 256
  const int V = 1024;                                         // fixed by problem
  const int T = (int)((size_t)in_sizes[0] / ((size_t)B * V)); // 2000

  // workspace: El (B*T*S f32) | Eb (B*T f32) | nll (B f32)  ~= 63 MiB
  float* El = (float*)d_ws;
  float* Eb = El + (size_t)B * T * S;
  float* nw = Eb + (size_t)B * T;

  dim3 g1(T, B);
  k_gather_exp<<<g1, 256, 0, stream>>>(lp, tgt, ilen, El, Eb, T, V, S);
  k_ctc_alpha<<<B, 64, 0, stream>>>(El, Eb, tgt, ilen, tlen, nw, T, S);
  k_reduce<<<1, 64, 0, stream>>>(nw, (float*)d_out, B);
}

// Round 2
// 579.603 us; speedup vs baseline: 1.1067x; 1.1067x over previous
//
#include <hip/hip_runtime.h>
#include <stdint.h>

// CTC loss forward, MI355X.
// Phase 1 (k_gather_exp): direct-gather emission compaction.
//   El[b][t][d] = exp(lp[b,t,tgt[b,d]]), Eb[b][t] = exp(lp[b,t,0]).
// Phase 2 (k_ctc_alpha): one wave per sample; linear-domain alpha with
//   per-lane power-of-2 offsets. Cross-lane shift-by-1 via DPP wave_shr1
//   (VALU latency) instead of ds_bpermute (~120 cyc). Emissions staged to
//   LDS in 32-step double-buffered chunks (global_load_lds), then to
//   registers in 4-step groups (double-buffered) to hide ds_read latency.
// Phase 3 (k_reduce): mean over batch of nll/target_length.

#define CS 32
#define TT 8
#define LN2F 0.69314718055994530942f

#define ASYNC_CP16(g, l)                                                     \
  __builtin_amdgcn_global_load_lds(                                          \
      (__attribute__((address_space(1))) void*)(g),                          \
      (__attribute__((address_space(3))) void*)(l), 16, 0, 0)
#define ASYNC_CP4(g, l)                                                      \
  __builtin_amdgcn_global_load_lds(                                          \
      (__attribute__((address_space(1))) void*)(g),                          \
      (__attribute__((address_space(3))) void*)(l), 4, 0, 0)

// lane i <- lane i-1, lane 0 <- 0 (DPP wave_shr1, bound_ctrl=1)
__device__ __forceinline__ float shr1f(float x) {
  return __int_as_float(
      __builtin_amdgcn_update_dpp(0, __float_as_int(x), 0x138, 0xF, 0xF, true));
}
__device__ __forceinline__ int shr1i(int x) {
  return __builtin_amdgcn_update_dpp(0, x, 0x138, 0xF, 0xF, true);
}

__global__ __launch_bounds__(256) void k_gather_exp(
    const float* __restrict__ lp, const int* __restrict__ tgt,
    const int* __restrict__ ilen, float* __restrict__ El,
    float* __restrict__ Eb, int T, int V, int S) {
  const int b = blockIdx.y;
  const int t0 = blockIdx.x * TT;
  const int tid = threadIdx.x;
  __shared__ int labs[256];
  labs[tid] = tgt[b * S + tid];  // S == 256 == blockDim
  const int Tb = ilen[b];
  __syncthreads();
  const int rn = min(TT, Tb - t0);
  if (rn <= 0) return;
  const int lab = labs[tid];
  const float* rowp = lp + ((size_t)b * T + t0) * V;
  float* outp = El + ((size_t)b * T + t0) * S + tid;
  if (rn == TT) {
    float v[TT];
#pragma unroll
    for (int r = 0; r < TT; ++r) v[r] = rowp[(size_t)r * V + lab];
#pragma unroll
    for (int r = 0; r < TT; ++r) outp[(size_t)r * S] = __expf(v[r]);
  } else {
    for (int r = 0; r < rn; ++r) outp[(size_t)r * S] = __expf(rowp[(size_t)r * V + lab]);
  }
  if (tid < rn) Eb[(size_t)b * T + t0 + tid] = __expf(rowp[(size_t)tid * V]);
}

__global__ __launch_bounds__(64) void k_ctc_alpha(
    const float* __restrict__ El, const float* __restrict__ Eb,
    const int* __restrict__ tgt, const int* __restrict__ ilen,
    const int* __restrict__ tlen, float* __restrict__ nll_out, int T, int S) {
  const int b = blockIdx.x;
  const int lane = threadIdx.x;
  const bool l0 = (lane == 0);
  __shared__ __align__(16) float elbuf[2][CS][256];
  __shared__ float ebbuf[2][CS];

  const int Tb = ilen[b];
  const int U = tlen[b];

  // skip flags per pair p = 4*lane + j
  const int4 tg = *(const int4*)(tgt + (size_t)b * S + 4 * lane);
  const int tprev = __shfl_up(tg.w, 1);
  const float sk0 = (l0 || tg.x != tprev) ? 1.0f : 0.0f;
  const float sk1 = (tg.y != tg.x) ? 1.0f : 0.0f;
  const float sk2 = (tg.z != tg.y) ? 1.0f : 0.0f;
  const float sk3 = (tg.w != tg.z) ? 1.0f : 0.0f;

  // lane owns pairs p=4*lane..4*lane+3 (states 2p+1 label, 2p+2 blank);
  // a0 = state 0 (lane 0 only). true alpha = a * 2^o (per-lane offset).
  float aL0 = 0, aL1 = 0, aL2 = 0, aL3 = 0;
  float aB0 = 0, aB1 = 0, aB2 = 0, aB3 = 0;
  float a0 = 0;
  int o = 0;
  float s = 1.0f;  // 2^(o_left - o)

  const float* Elb = El + (size_t)b * T * 256;
  const float* Ebb = Eb + (size_t)b * T;

  {  // issue chunk 0
    const int nrows = min(CS, T);
    for (int r = 0; r < nrows; ++r)
      ASYNC_CP16(Elb + (size_t)r * 256 + 4 * lane, &elbuf[0][r][0]);
    if (lane < nrows) ASYNC_CP4(Ebb + lane, &ebbuf[0][0]);
  }

  auto stepf = [&](float4 el, float eb) {  // t > 0 body
    float pL = shr1f(aL3) * s;  // state 2p-1 for p = 4*lane
    float pB = shr1f(aB3) * s;  // state 2p
    pL = l0 ? 0.0f : pL;
    pB = l0 ? a0 : pB;
    const float nB0 = (aB0 + aL0) * eb;
    const float nB1 = (aB1 + aL1) * eb;
    const float nB2 = (aB2 + aL2) * eb;
    const float nB3 = (aB3 + aL3) * eb;
    const float nL0 = (aL0 + pB + sk0 * pL) * el.x;
    const float nL1 = (aL1 + aB0 + sk1 * aL0) * el.y;
    const float nL2 = (aL2 + aB1 + sk2 * aL1) * el.z;
    const float nL3 = (aL3 + aB2 + sk3 * aL2) * el.w;
    a0 *= eb;
    aL0 = nL0; aL1 = nL1; aL2 = nL2; aL3 = nL3;
    aB0 = nB0; aB1 = nB1; aB2 = nB2; aB3 = nB3;
  };
  auto renorm = [&]() {  // per-lane power-of-2 rescale (no transcendentals)
    float m = fmaxf(fmaxf(fmaxf(aL0, aL1), fmaxf(aL2, aL3)),
                    fmaxf(fmaxf(aB0, aB1), fmaxf(aB2, aB3)));
    m = fmaxf(m, a0);
    const bool nz = (m > 0.0f);
    const int mk = nz ? (((__float_as_int(m) >> 23) & 0xff) - 126) : 0;
    const int ocand = o + mk;
    const int oleft = shr1i(ocand);
    o = (nz || l0) ? ocand : oleft;  // zero lanes adopt left offset
    const float sc = nz ? __int_as_float((127 - mk) << 23) : 1.0f;
    aL0 *= sc; aL1 *= sc; aL2 *= sc; aL3 *= sc;
    aB0 *= sc; aB1 *= sc; aB2 *= sc; aB3 *= sc;
    a0 *= sc;
    int d = shr1i(o) - o;
    d = max(-126, min(126, d));
    s = __int_as_float((d + 127) << 23);  // 2^d
  };

  const int nchunks = (Tb + CS - 1) / CS;
  for (int c = 0; c < nchunks; ++c) {
    asm volatile("s_waitcnt vmcnt(0)" ::: "memory");
    __syncthreads();
    const int buf = c & 1;
    if ((c + 1) * CS < Tb) {  // prefetch next chunk into other LDS buffer
      const int base = (c + 1) * CS;
      const int nrows = min(CS, T - base);
      const float* gEl = Elb + (size_t)base * 256 + 4 * lane;
      for (int r = 0; r < nrows; ++r)
        ASYNC_CP16(gEl + (size_t)r * 256, &elbuf[buf ^ 1][r][0]);
      if (lane < nrows) ASYNC_CP4(Ebb + base + lane, &ebbuf[buf ^ 1][0]);
    }
    const int nsteps = min(CS, Tb - c * CS);

    // register double-buffer: 4-step emission groups
    float4 ce[4]; float cb[4];
#pragma unroll
    for (int j = 0; j < 4; ++j) {
      ce[j] = *(const float4*)&elbuf[buf][j][4 * lane];
      cb[j] = ebbuf[buf][j];
    }
    for (int g = 0; g < nsteps; g += 4) {
      float4 ne[4]; float nb[4];
      const bool pf = (g + 4 < CS);
      if (pf) {
#pragma unroll
        for (int j = 0; j < 4; ++j) {
          ne[j] = *(const float4*)&elbuf[buf][g + 4 + j][4 * lane];
          nb[j] = ebbuf[buf][g + 4 + j];
        }
      }
      if (g + 4 <= nsteps) {  // full group (common case)
        if (c == 0 && g == 0) {
          a0 = l0 ? cb[0] : 0.0f;   // t = 0 init
          aL0 = l0 ? ce[0].x : 0.0f;
          aL1 = aL2 = aL3 = aB0 = aB1 = aB2 = aB3 = 0.0f;
          stepf(ce[1], cb[1]); stepf(ce[2], cb[2]); stepf(ce[3], cb[3]);
        } else {
          stepf(ce[0], cb[0]); stepf(ce[1], cb[1]);
          stepf(ce[2], cb[2]); stepf(ce[3], cb[3]);
        }
        renorm();
      } else {  // tail group
#pragma unroll
        for (int j = 0; j < 4; ++j) {
          if (g + j < nsteps) {
            if (c == 0 && g == 0 && j == 0) {
              a0 = l0 ? cb[0] : 0.0f;
              aL0 = l0 ? ce[0].x : 0.0f;
              aL1 = aL2 = aL3 = aB0 = aB1 = aB2 = aB3 = 0.0f;
            } else {
              stepf(ce[j], cb[j]);
            }
          }
        }
      }
      if (pf) {
#pragma unroll
        for (int j = 0; j < 4; ++j) { ce[j] = ne[j]; cb[j] = nb[j]; }
      }
    }
  }

  // alpha_{Tb-1} at states 2U (pair U-1 blank) and 2U-1 (pair U-1 label)
  if (lane == ((U - 1) >> 2)) {
    const int j = (U - 1) & 3;
    float sv;
    if (j == 0)      sv = aL0 + aB0;
    else if (j == 1) sv = aL1 + aB1;
    else if (j == 2) sv = aL2 + aB2;
    else             sv = aL3 + aB3;
    float nll = -LN2F * (__log2f(sv) + (float)o);
    if (!(nll < 5e29f)) nll = 0.0f;  // zero_infinity (catches NaN/inf)
    nll_out[b] = nll / (float)U;
  }
}

__global__ __launch_bounds__(64) void k_reduce(const float* __restrict__ nll,
                                               float* __restrict__ out,
                                               int B) {
  float v = 0.0f;
  for (int i = threadIdx.x; i < B; i += 64) v += nll[i];
  for (int off = 32; off > 0; off >>= 1) v += __shfl_down(v, off);
  if (threadIdx.x == 0) out[0] = v / (float)B;
}

extern "C" void kernel_launch(void* const* d_in, const int* in_sizes, int n_in,
                              void* d_out, int out_size, void* d_ws,
                              size_t ws_size, hipStream_t stream) {
  const float* lp = (const float*)d_in[0];
  const int* tgt = (const int*)d_in[1];
  const int* ilen = (const int*)d_in[2];
  const int* tlen = (const int*)d_in[3];

  const int B = in_sizes[2];
  const int S = in_sizes[1] / B;                               // 256
  const int V = 1024;                                          // fixed by problem
  const int T = (int)((size_t)in_sizes[0] / ((size_t)B * V));  // 2000

  float* El = (float*)d_ws;                 // B*T*S f32
  float* Eb = El + (size_t)B * T * S;       // B*T f32
  float* nw = Eb + (size_t)B * T;           // B f32

  dim3 g1((T + TT - 1) / TT, B);
  k_gather_exp<<<g1, 256, 0, stream>>>(lp, tgt, ilen, El, Eb, T, V, S);
  k_ctc_alpha<<<B, 64, 0, stream>>>(El, Eb, tgt, ilen, tlen, nw, T, S);
  k_reduce<<<1, 64, 0, stream>>>(nw, (float*)d_out, B);
}

// Round 3
// 512.915 us; speedup vs baseline: 1.2506x; 1.1300x over previous
//
#include <hip/hip_runtime.h>
#include <stdint.h>

// CTC loss forward, MI355X.
// Phase 1 (k_gather_exp): block per (b,t) row; direct global gather of the
//   256 target emissions + blank, exp(), coalesced compact store.
//   El[b][t][d] = exp(lp[b,t,tgt[b,d]]), Eb[b][t] = exp(lp[b,t,0]).
// Phase 2 (k_ctc_alpha): one wave per sample; linear-domain alpha with
//   per-lane power-of-2 offsets (renorm every 4 steps, no transcendentals).
//   Emissions streamed global->REGISTERS via a 16-step rotating pipeline
//   (static slot indices, unroll-by-16): lane i loads El[t][4i..4i+3] as one
//   coalesced dwordx4, Eb[t] is a wave-uniform (scalar) load. No LDS, no
//   barriers, no vmcnt(0) drains -- compiler emits fine-grained vmcnt waits.
//   Cross-lane shift-by-1 via DPP wave_shr1 (VALU latency, not DS).
// Phase 3 (k_reduce): mean over batch of nll/target_length.

#define LN2F 0.69314718055994530942f
#define PD 16  // register pipeline depth (steps)

// lane i <- lane i-1, lane 0 <- 0 (DPP wave_shr1, bound_ctrl=1)
__device__ __forceinline__ float shr1f(float x) {
  return __int_as_float(
      __builtin_amdgcn_update_dpp(0, __float_as_int(x), 0x138, 0xF, 0xF, true));
}
__device__ __forceinline__ int shr1i(int x) {
  return __builtin_amdgcn_update_dpp(0, x, 0x138, 0xF, 0xF, true);
}

__global__ __launch_bounds__(256) void k_gather_exp(
    const float* __restrict__ lp, const int* __restrict__ tgt,
    const int* __restrict__ ilen, float* __restrict__ El,
    float* __restrict__ Eb, int T, int V, int S) {
  const int b = blockIdx.y;
  const int t = blockIdx.x;
  if (t >= ilen[b]) return;  // phase 2 never reads t >= T_b
  const int tid = threadIdx.x;               // S == 256 == blockDim
  const int lab = tgt[b * S + tid];
  const float* row = lp + ((size_t)b * T + t) * V;
  El[((size_t)b * T + t) * S + tid] = __expf(row[lab]);
  if (tid == 0) Eb[(size_t)b * T + t] = __expf(row[0]);
}

__global__ __launch_bounds__(64) void k_ctc_alpha(
    const float* __restrict__ El, const float* __restrict__ Eb,
    const int* __restrict__ tgt, const int* __restrict__ ilen,
    const int* __restrict__ tlen, float* __restrict__ nll_out, int T, int S) {
  const int b = blockIdx.x;
  const int lane = threadIdx.x;
  const bool l0 = (lane == 0);

  const int Tb = ilen[b];
  const int U = tlen[b];

  // skip flags per pair p = 4*lane + j
  const int4 tg = *(const int4*)(tgt + (size_t)b * S + 4 * lane);
  const int tprev = __shfl_up(tg.w, 1);
  const float sk0 = (l0 || tg.x != tprev) ? 1.0f : 0.0f;
  const float sk1 = (tg.y != tg.x) ? 1.0f : 0.0f;
  const float sk2 = (tg.z != tg.y) ? 1.0f : 0.0f;
  const float sk3 = (tg.w != tg.z) ? 1.0f : 0.0f;

  const float* Elb = El + (size_t)b * T * 256;
  const float* Ebb = Eb + (size_t)b * T;

  // lane owns pairs p=4*lane..4*lane+3 (states 2p+1 label, 2p+2 blank);
  // a0 = state 0 (lane 0 only). true alpha = a * 2^o (per-lane offset).
  // t = 0 init: only states 0,1 live.
  float a0 = l0 ? Ebb[0] : 0.0f;
  float aL0 = l0 ? Elb[0] : 0.0f;
  float aL1 = 0, aL2 = 0, aL3 = 0;
  float aB0 = 0, aB1 = 0, aB2 = 0, aB3 = 0;
  int o = 0;
  float s = 1.0f;  // 2^(o_left - o)

  auto stepf = [&](float4 el, float eb) {  // generic step (t > 0)
    float pL = shr1f(aL3) * s;  // state 2p-1 for p = 4*lane
    float pB = shr1f(aB3) * s;  // state 2p
    pL = l0 ? 0.0f : pL;
    pB = l0 ? a0 : pB;
    const float nB0 = (aB0 + aL0) * eb;
    const float nB1 = (aB1 + aL1) * eb;
    const float nB2 = (aB2 + aL2) * eb;
    const float nB3 = (aB3 + aL3) * eb;
    const float nL0 = (aL0 + fmaf(sk0, pL, pB)) * el.x;
    const float nL1 = (aL1 + fmaf(sk1, aL0, aB0)) * el.y;
    const float nL2 = (aL2 + fmaf(sk2, aL1, aB1)) * el.z;
    const float nL3 = (aL3 + fmaf(sk3, aL2, aB2)) * el.w;
    a0 *= eb;
    aL0 = nL0; aL1 = nL1; aL2 = nL2; aL3 = nL3;
    aB0 = nB0; aB1 = nB1; aB2 = nB2; aB3 = nB3;
  };
  auto renorm = [&]() {  // per-lane power-of-2 rescale (no transcendentals)
    float m = fmaxf(fmaxf(fmaxf(aL0, aL1), fmaxf(aL2, aL3)),
                    fmaxf(fmaxf(aB0, aB1), fmaxf(aB2, aB3)));
    m = fmaxf(m, a0);
    const bool nz = (m > 0.0f);
    const int mk = nz ? (((__float_as_int(m) >> 23) & 0xff) - 126) : 0;
    const int ocand = o + mk;
    const int oleft = shr1i(ocand);
    o = (nz || l0) ? ocand : oleft;  // zero lanes adopt left offset
    const float sc = nz ? __int_as_float((127 - mk) << 23) : 1.0f;
    aL0 *= sc; aL1 *= sc; aL2 *= sc; aL3 *= sc;
    aB0 *= sc; aB1 *= sc; aB2 *= sc; aB3 *= sc;
    a0 *= sc;
    int d = shr1i(o) - o;
    d = max(-126, min(126, d));
    s = __int_as_float((d + 127) << 23);  // 2^d
  };

  // register pipeline: slot j holds emissions for row t = base + j
  float4 pel[PD];
  float peb[PD];
  const int lo4 = 4 * lane;

#pragma unroll
  for (int j = 0; j < PD; ++j) {  // prologue: rows 1..16 (Tb >= 17 assumed)
    const int row = min(j + 1, Tb - 1);
    pel[j] = *(const float4*)(Elb + ((size_t)row << 8) + lo4);
    peb[j] = Ebb[row];
  }

  const int R = Tb - 1;       // generic steps t = 1..Tb-1
  const int nfull = R >> 4;
  const int rem = R & 15;

  for (int k = 0; k < nfull; ++k) {
    const int base = 1 + (k << 4);
#pragma unroll
    for (int j = 0; j < PD; ++j) {
      const float4 el = pel[j];
      const float eb = peb[j];
      const int row = min(base + PD + j, Tb - 1);  // refill slot j
      pel[j] = *(const float4*)(Elb + ((size_t)row << 8) + lo4);
      peb[j] = Ebb[row];
      stepf(el, eb);
      // t = base + j, base ≡ 1 (mod 16) → (t&3)==3 ⇔ (j&3)==2
      if ((j & 3) == 2) renorm();
    }
  }
  {  // tail: remaining rem steps, slots 0..rem-1 already loaded
#pragma unroll
    for (int j = 0; j < PD; ++j) {
      if (j < rem) {
        stepf(pel[j], peb[j]);
        if ((j & 3) == 2) renorm();
      }
    }
  }

  // alpha_{Tb-1} at states 2U (pair U-1 blank) and 2U-1 (pair U-1 label)
  if (lane == ((U - 1) >> 2)) {
    const int j = (U - 1) & 3;
    float sv;
    if (j == 0)      sv = aL0 + aB0;
    else if (j == 1) sv = aL1 + aB1;
    else if (j == 2) sv = aL2 + aB2;
    else             sv = aL3 + aB3;
    float nll = -LN2F * (__log2f(sv) + (float)o);
    if (!(nll < 5e29f)) nll = 0.0f;  // zero_infinity (catches NaN/inf)
    nll_out[b] = nll / (float)U;
  }
}

__global__ __launch_bounds__(64) void k_reduce(const float* __restrict__ nll,
                                               float* __restrict__ out,
                                               int B) {
  float v = 0.0f;
  for (int i = threadIdx.x; i < B; i += 64) v += nll[i];
  for (int off = 32; off > 0; off >>= 1) v += __shfl_down(v, off);
  if (threadIdx.x == 0) out[0] = v / (float)B;
}

extern "C" void kernel_launch(void* const* d_in, const int* in_sizes, int n_in,
                              void* d_out, int out_size, void* d_ws,
                              size_t ws_size, hipStream_t stream) {
  const float* lp = (const float*)d_in[0];
  const int* tgt = (const int*)d_in[1];
  const int* ilen = (const int*)d_in[2];
  const int* tlen = (const int*)d_in[3];

  const int B = in_sizes[2];
  const int S = in_sizes[1] / B;                               // 256
  const int V = 1024;                                          // fixed by problem
  const int T = (int)((size_t)in_sizes[0] / ((size_t)B * V));  // 2000

  float* El = (float*)d_ws;                 // B*T*S f32
  float* Eb = El + (size_t)B * T * S;       // B*T f32
  float* nw = Eb + (size_t)B * T;           // B f32

  dim3 g1(T, B);
  k_gather_exp<<<g1, 256, 0, stream>>>(lp, tgt, ilen, El, Eb, T, V, S);
  k_ctc_alpha<<<B, 64, 0, stream>>>(El, Eb, tgt, ilen, tlen, nw, T, S);
  k_reduce<<<1, 64, 0, stream>>>(nw, (float*)d_out, B);
}